// Round 12
// baseline (153.905 us; speedup 1.0000x reference)
//
#include <hip/hip_runtime.h>
#include <hip/hip_bf16.h>

// Problem constants (B,T,D,P,ALPHA,PR) = (4,4096,1024,512,4,64)
#define Bb 4
#define Tt 4096
#define Dd 1024
#define Pp 512
#define PRr 64
#define Mm (Bb*Tt)   // 16384
#define NCH 256      // scan chunks per batch
#define CL  16       // chunk length = Tt/NCH

typedef __bf16 bf16;
typedef __bf16 bf16x8 __attribute__((ext_vector_type(8)));
typedef __bf16 bf16x4 __attribute__((ext_vector_type(4)));
typedef float f32x4 __attribute__((ext_vector_type(4)));

#define GPTR(p) (const __attribute__((address_space(1))) void*)(p)
#define LPTR(p) (__attribute__((address_space(3))) void*)(p)

__device__ __forceinline__ float sigmoidf_(float x) {
    return 1.0f / (1.0f + __expf(-x));
}

// ---------------- prep kernels (weights -> bf16, pre-transposed to N x K) ----

// Merged: W1t [0,4096) + W3t [4096,4608) + CW zero [4608,4672) + flags zero [4672]
__global__ void prep_all(const float* __restrict__ W_toP, const float* __restrict__ W_U,
                         const float* __restrict__ W_V, const float* __restrict__ W_F,
                         const float* __restrict__ B_mat, const float* __restrict__ W_lam,
                         bf16* __restrict__ W1t, bf16* __restrict__ W3t,
                         float* __restrict__ CW, unsigned int* __restrict__ flags) {
    int bid = blockIdx.x;
    if (bid < 4096) {
        int idx = bid * 256 + threadIdx.x;      // 1024*1024
        int n = idx >> 10, k = idx & 1023;
        float v;
        if (n < Pp) {
            int p = n;
            float4 u  = *(const float4*)(W_U + ((size_t)k * Pp + p) * 4);
            float4 wv = *(const float4*)(W_V + (size_t)p * 4);
            v = W_toP[(size_t)k * Pp + p] + u.x * wv.x + u.y * wv.y + u.z * wv.z + u.w * wv.w;
        } else {
            v = W_F[(size_t)k * Pp + (n - Pp)];
        }
        W1t[idx] = (bf16)v;
    } else if (bid < 4608) {
        int idx = (bid - 4096) * 256 + threadIdx.x;   // 128*1024
        int n = idx >> 10, k = idx & 1023;
        float v = 0.0f;
        if (n < PRr) { if (k < Pp) v = B_mat[(size_t)k * PRr + n]; }
        else         { if (k >= Pp) v = W_lam[(size_t)(k - Pp) * PRr + (n - PRr)]; }
        W3t[idx] = (bf16)v;
    } else if (bid < 4672) {
        int i = (bid - 4608) * 256 + threadIdx.x;     // 64 blocks: 16384 f32x4
        ((f32x4*)CW)[i] = (f32x4){};
    } else {
        flags[threadIdx.x] = 0u;                      // 256 lookback flags
    }
}

// CW = C_mat (PR x P) @ W_fromP (P x D), split-K atomics.
// grid (4 col-chunks, 64 r, 8 p-chunks) = 2048 blocks x 256 thr.
__global__ void prep_cw(const float* __restrict__ C_mat, const float* __restrict__ W_fromP,
                        float* __restrict__ CW) {
    __shared__ float crow[64];
    int nc = blockIdx.x;           // 4
    int r  = blockIdx.y;           // 64
    int pc = blockIdx.z;           // 8
    int tid = threadIdx.x;         // 256
    if (tid < 64) crow[tid] = C_mat[(size_t)r * Pp + pc * 64 + tid];
    __syncthreads();
    int n = nc * 256 + tid;
    float acc = 0.0f;
    #pragma unroll 8
    for (int i = 0; i < 64; ++i)
        acc = fmaf(crow[i], W_fromP[(size_t)(pc * 64 + i) * Dd + n], acc);
    atomicAdd(&CW[(size_t)r * Dd + n], acc);
}

__global__ void prep_w2(const float* __restrict__ W_fromP, const float* __restrict__ CW,
                        bf16* __restrict__ W2t) {
    int n = blockIdx.x;          // 1024
    int k = threadIdx.x;         // 576
    float v = (k < Pp) ? W_fromP[(size_t)k * Dd + n]
                       : CW[(size_t)(k - Pp) * Dd + n];
    W2t[(size_t)n * 576 + k] = (bf16)v;
}

// ---------------- fused scan: s_t = lam_t * s_{t-1} + u_t (one kernel) ------
// Decoupled lookback. Grid (64 chunk-groups, Bb) = 256 blocks (all co-resident
// -> spin-wait is deadlock-free), 256 threads = (chunk ci = tid>>6, r = tid&63).
// Local scans held in registers (no slocal/pprod global round-trip). Block
// aggregate (S,P) per r published with agent-scope release flag; lookback is a
// parallel spin (thread t polls flag[t]) + 4 waves composing 16 predecessors
// each from coalesced agg loads + 4-way LDS combine. Carry applied in-reg,
// sb written directly.
__global__ void scan_fused(const float* __restrict__ UL,
                           float* __restrict__ aggS, float* __restrict__ aggP,
                           unsigned int* __restrict__ flags,
                           bf16* __restrict__ sb) {
    int cg = blockIdx.x;            // 0..63
    int b  = blockIdx.y;            // 0..3
    int tid = threadIdx.x;
    int ci = tid >> 6;              // chunk within group: 0..3
    int r  = tid & 63;
    int c  = cg * 4 + ci;           // global chunk 0..255
    const float* ulb = UL + ((size_t)b * Tt + (size_t)c * CL) * 128;

    float uv[CL], lv[CL];
    #pragma unroll
    for (int i = 0; i < CL; i++) {
        uv[i] = ulb[(size_t)i * 128 + r];
        lv[i] = ulb[(size_t)i * 128 + 64 + r];
    }
    float sv[CL], pv[CL];
    float s = 0.0f, p = 1.0f;
    #pragma unroll
    for (int i = 0; i < CL; i++) {
        s = fmaf(lv[i], s, uv[i]);
        p *= lv[i];
        sv[i] = s; pv[i] = p;
    }

    __shared__ float shS[4][64], shP[4][64];
    __shared__ float rS[4][64], rP[4][64];
    __shared__ float shC[64];
    shS[ci][r] = s; shP[ci][r] = p;
    __syncthreads();

    // forward-compose chunks 0..3; record prefix transform before own chunk
    float accS = 0.0f, accP = 1.0f, preS = 0.0f, preP = 1.0f;
    #pragma unroll
    for (int j = 0; j < 4; j++) {
        if (j == ci) { preS = accS; preP = accP; }
        accS = fmaf(shP[j][r], accS, shS[j][r]);
        accP *= shP[j][r];
    }
    // accS/accP = block aggregate transform

    // publish aggregate (wave 0), release flag
    if (ci == 0) {
        int slot = (b * 64 + cg) * 64 + r;
        aggS[slot] = accS;
        aggP[slot] = accP;
        __threadfence();
        if (r == 0)
            __hip_atomic_store(&flags[b * 64 + cg], 1u,
                               __ATOMIC_RELEASE, __HIP_MEMORY_SCOPE_AGENT);
    }

    // parallel spin on all predecessor flags
    if (tid < cg) {
        while (__hip_atomic_load(&flags[b * 64 + tid],
                                 __ATOMIC_ACQUIRE, __HIP_MEMORY_SCOPE_AGENT) == 0) {}
    }
    __syncthreads();
    __threadfence();   // acquire ordering for every thread's agg loads

    // 4 waves compose 16 predecessors each (coalesced over r)
    int w = ci;
    float wS = 0.0f, wP = 1.0f;
    int j0 = w * 16;
    int j1 = j0 + 16 < cg ? j0 + 16 : cg;
    for (int j = j0; j < j1; ++j) {
        float Sj = aggS[(b * 64 + j) * 64 + r];
        float Pj = aggP[(b * 64 + j) * 64 + r];
        wS = fmaf(Pj, wS, Sj);
        wP *= Pj;
    }
    rS[w][r] = wS; rP[w][r] = wP;
    __syncthreads();
    if (ci == 0) {
        float x = 0.0f;
        #pragma unroll
        for (int w2 = 0; w2 < 4; ++w2) x = fmaf(rP[w2][r], x, rS[w2][r]);
        shC[r] = x;    // carry entering this block
    }
    __syncthreads();

    float x   = shC[r];
    float cin = fmaf(preP, x, preS);   // carry entering chunk ci
    bf16* sbo = sb + ((size_t)b * Tt + (size_t)c * CL) * PRr;
    #pragma unroll
    for (int i = 0; i < CL; i++)
        sbo[(size_t)i * PRr + r] = (bf16)fmaf(pv[i], cin, sv[i]);
}

// ---------------- 256x256 GEMM, 8-phase schedule (R10, frozen) --------------
// A row-major (M x K) bf16, split at ksplit between A0/A1 (tile-aligned);
// OR (AF32=1) A = Af in f32, reg-staged with on-the-fly bf16 convert.
// AF32 v3: HALF-TILE reg buffers H0,H1 (16 regs each = 32 total; no spill,
// VGPR 124) with 4-phase issue->write slack:
//   ph2(t): writeH0 (issued ph2(t-1), ~1400cyc slack > ~900cyc HBM), issue H0(t+2)
//   ph3(t): writeH1 (issued ph3(t-1)), issue H1(t+2), vmcnt(8) retires B(t+1)
// Measured R10/R11: GEMM1 ~57us, FETCH 41MB clean, MfmaUtil 22-23.
// AF32=0 path: exact R5 loop (45.7us measured). T2 swizzle both sides.
template <int EPI, int AF32>  // EPI 0: bf16 out + sigmoid col>=sigcol ; 2: f32 plain
__global__ __launch_bounds__(512, 2) void gemm256(
    const bf16* __restrict__ A0, int lda0,
    const bf16* __restrict__ A1, int lda1, int ksplit,
    const float* __restrict__ Af,
    const bf16* __restrict__ Bt, int ldb, int K,
    void* __restrict__ Cout, int ldc, int sigcol) {

    __shared__ bf16 As[2][256 * 64];
    __shared__ bf16 Bs[2][256 * 64];

    const int tid  = threadIdx.x;
    const int lane = tid & 63;
    const int wid  = tid >> 6;
    const int wm   = wid >> 2;        // 0..1
    const int wn   = wid & 3;         // 0..3

    // bijective XCD swizzle (grid multiple of 8)
    const int cpx = gridDim.x >> 3;
    const int bid = blockIdx.x;
    const int swz = (bid & 7) * cpx + (bid >> 3);
    const int mBase = (swz >> 2) * 256;
    const int nBase = (swz & 3) * 256;

    const int lr  = lane & 15;
    const int q16 = (lane >> 4) * 16;   // byte col offset of fragment

    auto srcA = [&](int kt, const bf16*& src, int& lda, int& kc) {
        if (kt < ksplit) { src = A0; lda = lda0; kc = kt; }
        else             { src = A1; lda = lda1; kc = kt - ksplit; }
    };

    // stage one 8KB round: linear LDS dest, inverse-swizzled global src (rule 21)
    auto stage = [&](const bf16* src, int lda, int kc, int rowBase, bf16* lbuf, int rd) {
        int d = rd * 8192 + tid * 16;             // phys byte (linear)
        int L = d ^ (((d >> 7) & 7) << 4);        // logical byte
        int r = L >> 7;
        int c = (L & 127) >> 1;
        const bf16* g = src + (size_t)(rowBase + r) * lda + (kc + c);
        __builtin_amdgcn_global_load_lds(GPTR(g), LPTR((char*)lbuf + d), 16, 0, 0);
    };

    auto frag = [&](const bf16* lbuf, int r, int cb) -> bf16x8 {
        int flat = r * 128 + cb;
        int phys = flat ^ (((flat >> 7) & 7) << 4);
        return *(const bf16x8*)((const char*)lbuf + phys);
    };

    // AF32 A-path: per-round logical (row,col) for this thread's 16B dest slot
    int rrA[4], ccA[4];
    #pragma unroll
    for (int rd = 0; rd < 4; ++rd) {
        int d = rd * 8192 + tid * 16;
        int L = d ^ (((d >> 7) & 7) << 4);
        rrA[rd] = L >> 7;
        ccA[rd] = (L & 127) >> 1;
    }
    f32x4 H0[4], H1[4];   // two half-tile staging buffers (rounds 0,1 / 2,3)

    auto issueH = [&](f32x4 (&v)[4], int kc, int rdb) {
        #pragma unroll
        for (int rd = 0; rd < 2; ++rd) {
            const float* g = Af + (size_t)(mBase + rrA[rdb + rd]) * Dd + kc + ccA[rdb + rd];
            v[2 * rd]     = *(const f32x4*)(g);
            v[2 * rd + 1] = *(const f32x4*)(g + 4);
        }
        asm volatile("" ::: "memory");   // pin loads here
    };
    auto writeH = [&](f32x4 (&v)[4], bf16* lbuf, int rdb) {
        #pragma unroll
        for (int rd = 0; rd < 2; ++rd) {
            bf16x8 o;
            #pragma unroll
            for (int j = 0; j < 4; ++j) {
                o[j]     = (bf16)v[2 * rd][j];
                o[j + 4] = (bf16)v[2 * rd + 1][j];
            }
            *(bf16x8*)((char*)lbuf + (rdb + rd) * 8192 + tid * 16) = o;
        }
    };

    const int NT = K / 64;

    // prologue
    if (AF32) {
        issueH(H0, 0, 0); issueH(H1, 0, 2);
        stage(Bt, ldb, 0, nBase, Bs[0], 0); stage(Bt, ldb, 0, nBase, Bs[0], 1);
        stage(Bt, ldb, 0, nBase, Bs[0], 2); stage(Bt, ldb, 0, nBase, Bs[0], 3);
        writeH(H0, As[0], 0);                // auto vmcnt: waits H0
        writeH(H1, As[0], 2);                // auto vmcnt: waits H1
        if (NT > 1) { issueH(H0, 64, 0); issueH(H1, 64, 2); }
        asm volatile("s_waitcnt lgkmcnt(0)" ::: "memory");
        if (NT > 1) asm volatile("s_waitcnt vmcnt(8)" ::: "memory");  // retire B(0)
        else        asm volatile("s_waitcnt vmcnt(0)" ::: "memory");
    } else {
        const bf16* sa; int la, kc; srcA(0, sa, la, kc);
        stage(sa, la, kc, mBase, As[0], 0); stage(sa, la, kc, mBase, As[0], 2);
        stage(Bt, ldb, 0, nBase, Bs[0], 0); stage(Bt, ldb, 0, nBase, Bs[0], 1);
        stage(Bt, ldb, 0, nBase, Bs[0], 2); stage(Bt, ldb, 0, nBase, Bs[0], 3);
        stage(sa, la, kc, mBase, As[0], 1); stage(sa, la, kc, mBase, As[0], 3);
        asm volatile("s_waitcnt vmcnt(2)" ::: "memory");
    }
    __builtin_amdgcn_s_barrier();

    f32x4 acc[8][4] = {};
    bf16x8 a[4], b0[4], b1[4];

#define MFMA16(AOFF, AV, BV)                                                          \
    _Pragma("unroll")                                                                 \
    for (int m_ = 0; m_ < 4; ++m_)                                                    \
        _Pragma("unroll")                                                             \
        for (int n_ = 0; n_ < 4; ++n_)                                                \
            acc[m_ + AOFF][n_] = __builtin_amdgcn_mfma_f32_16x16x32_bf16(             \
                AV[m_], BV[n_], acc[m_ + AOFF][n_], 0, 0, 0);

    if (AF32) {
        for (int t = 0; t < NT; ++t) {
            bf16* Ac = As[t & 1];       bf16* Bc = Bs[t & 1];
            bf16* An = As[(t + 1) & 1]; bf16* Bn = Bs[(t + 1) & 1];
            const bool hn  = (t + 1 < NT);
            const bool hn2 = (t + 2 < NT);
            const int ktn  = (t + 1) * 64;
            const int ktn2 = (t + 2) * 64;

            // ---- phase 0: G0 = (m0-3, kk0) ----
            #pragma unroll
            for (int i = 0; i < 4; ++i) a[i]  = frag(Ac, wm * 128 + i * 16 + lr, q16);
            #pragma unroll
            for (int i = 0; i < 4; ++i) b0[i] = frag(Bc, wn * 64 + i * 16 + lr, q16);
            if (hn) { stage(Bt, ldb, ktn, nBase, Bn, 0); stage(Bt, ldb, ktn, nBase, Bn, 1); }
            __builtin_amdgcn_s_barrier();
            __builtin_amdgcn_s_setprio(1);
            MFMA16(0, a, b0)
            __builtin_amdgcn_s_setprio(0);
            __builtin_amdgcn_s_barrier();

            // ---- phase 1: G1 = (m4-7, kk0) ----
            #pragma unroll
            for (int i = 0; i < 4; ++i) a[i] = frag(Ac, wm * 128 + (i + 4) * 16 + lr, q16);
            if (hn) { stage(Bt, ldb, ktn, nBase, Bn, 2); stage(Bt, ldb, ktn, nBase, Bn, 3); }
            __builtin_amdgcn_s_barrier();
            __builtin_amdgcn_s_setprio(1);
            MFMA16(4, a, b0)
            __builtin_amdgcn_s_setprio(0);
            __builtin_amdgcn_s_barrier();

            // ---- phase 2: G2 = (m0-3, kk1); writeH0 (4-phase slack), issue H0(t+2)
            #pragma unroll
            for (int i = 0; i < 4; ++i) a[i]  = frag(Ac, wm * 128 + i * 16 + lr, 64 + q16);
            #pragma unroll
            for (int i = 0; i < 4; ++i) b1[i] = frag(Bc, wn * 64 + i * 16 + lr, 64 + q16);
            if (hn)  writeH(H0, An, 0);            // auto vmcnt(8): retires H0
            if (hn2) issueH(H0, ktn2, 0);
            if (hn)  asm volatile("s_waitcnt lgkmcnt(0)" ::: "memory");
            __builtin_amdgcn_s_barrier();
            __builtin_amdgcn_s_setprio(1);
            MFMA16(0, a, b1)
            __builtin_amdgcn_s_setprio(0);
            __builtin_amdgcn_s_barrier();

            // ---- phase 3: G3 = (m4-7, kk1); writeH1, issue H1(t+2), retire B(t+1)
            #pragma unroll
            for (int i = 0; i < 4; ++i) a[i] = frag(Ac, wm * 128 + (i + 4) * 16 + lr, 64 + q16);
            if (hn)  writeH(H1, An, 2);            // auto vmcnt(8): retires H1
            if (hn2) issueH(H1, ktn2, 2);
            if (hn)  asm volatile("s_waitcnt lgkmcnt(0)" ::: "memory");
            if (hn2)      asm volatile("s_waitcnt vmcnt(8)" ::: "memory");  // retire B(t+1)
            else if (hn)  asm volatile("s_waitcnt vmcnt(0)" ::: "memory");  // tail drain
            __builtin_amdgcn_s_barrier();
            __builtin_amdgcn_s_setprio(1);
            MFMA16(4, a, b1)
            __builtin_amdgcn_s_setprio(0);
            __builtin_amdgcn_s_barrier();
        }
    } else {
        for (int t = 0; t < NT; ++t) {
            bf16* Ac = As[t & 1];       bf16* Bc = Bs[t & 1];
            bf16* An = As[(t + 1) & 1]; bf16* Bn = Bs[(t + 1) & 1];
            const bool hn = (t + 1 < NT);
            const bf16* sa = A0; int la = lda0, kc = 0;
            if (hn) srcA((t + 1) * 64, sa, la, kc);
            const int ktn = (t + 1) * 64;

            // ---- phase 0: G0 = (m0-3, kk0) ----
            #pragma unroll
            for (int i = 0; i < 4; ++i) a[i]  = frag(Ac, wm * 128 + i * 16 + lr, q16);
            #pragma unroll
            for (int i = 0; i < 4; ++i) b0[i] = frag(Bc, wn * 64 + i * 16 + lr, q16);
            if (hn) {
                stage(sa, la, kc, mBase, An, 0); stage(sa, la, kc, mBase, An, 2);
                asm volatile("s_waitcnt vmcnt(2)" ::: "memory");   // retire A1,A3 of cur
            } else {
                asm volatile("s_waitcnt vmcnt(0)" ::: "memory");   // last tile: drain
            }
            __builtin_amdgcn_s_barrier();
            __builtin_amdgcn_s_setprio(1);
            MFMA16(0, a, b0)
            __builtin_amdgcn_s_setprio(0);
            __builtin_amdgcn_s_barrier();

            // ---- phase 1: G1 = (m4-7, kk0) ----
            #pragma unroll
            for (int i = 0; i < 4; ++i) a[i] = frag(Ac, wm * 128 + (i + 4) * 16 + lr, q16);
            if (hn) { stage(Bt, ldb, ktn, nBase, Bn, 0); stage(Bt, ldb, ktn, nBase, Bn, 1); }
            __builtin_amdgcn_s_barrier();
            __builtin_amdgcn_s_setprio(1);
            MFMA16(4, a, b0)
            __builtin_amdgcn_s_setprio(0);
            __builtin_amdgcn_s_barrier();

            // ---- phase 2: G2 = (m0-3, kk1) ----
            #pragma unroll
            for (int i = 0; i < 4; ++i) a[i]  = frag(Ac, wm * 128 + i * 16 + lr, 64 + q16);
            #pragma unroll
            for (int i = 0; i < 4; ++i) b1[i] = frag(Bc, wn * 64 + i * 16 + lr, 64 + q16);
            if (hn) { stage(Bt, ldb, ktn, nBase, Bn, 2); stage(Bt, ldb, ktn, nBase, Bn, 3); }
            __builtin_amdgcn_s_barrier();
            __builtin_amdgcn_s_setprio(1);
            MFMA16(0, a, b1)
            __builtin_amdgcn_s_setprio(0);
            __builtin_amdgcn_s_barrier();

            // ---- phase 3: G3 = (m4-7, kk1) ----
            #pragma unroll
            for (int i = 0; i < 4; ++i) a[i] = frag(Ac, wm * 128 + (i + 4) * 16 + lr, 64 + q16);
            if (hn) {
                stage(sa, la, kc, mBase, An, 1); stage(sa, la, kc, mBase, An, 3);
                asm volatile("s_waitcnt vmcnt(2)" ::: "memory");   // retire A0,A2,B0..B3 of next
            }
            __builtin_amdgcn_s_barrier();
            __builtin_amdgcn_s_setprio(1);
            MFMA16(4, a, b1)
            __builtin_amdgcn_s_setprio(0);
            __builtin_amdgcn_s_barrier();
        }
    }
#undef MFMA16

    // epilogue
    const int lr4 = (lane >> 4) * 4;
    #pragma unroll
    for (int m = 0; m < 8; ++m) {
        #pragma unroll
        for (int n = 0; n < 4; ++n) {
            #pragma unroll
            for (int j = 0; j < 4; ++j) {
                int row = mBase + wm * 128 + m * 16 + lr4 + j;
                int col = nBase + wn * 64 + n * 16 + lr;
                float v = acc[m][n][j];
                if (EPI == 0) {
                    if (col >= sigcol) v = sigmoidf_(v);
                    ((bf16*)Cout)[(size_t)row * ldc + col] = (bf16)v;
                } else {
                    ((float*)Cout)[(size_t)row * ldc + col] = v;
                }
            }
        }
    }
}

// ---------------- 64x128 GEMM for GEMM2 (N=128): full-chip grid -------------
__global__ __launch_bounds__(256) void gemm_bt64(
    const bf16* __restrict__ A, int lda,
    const bf16* __restrict__ Bt, int K,
    float* __restrict__ Cout, int ldc, int sigcol) {

    __shared__ bf16 As[64][32];
    __shared__ bf16 Bs[128][32];

    const int tid  = threadIdx.x;
    const int lane = tid & 63;
    const int wid  = tid >> 6;
    const int wr   = (wid >> 1) * 32;
    const int wc   = (wid & 1) * 64;
    const int mBase = blockIdx.x * 64;

    f32x4 acc[2][4] = {};

    const int lr = lane & 15;
    const int lk = (lane >> 4) * 8;

    for (int kt = 0; kt < K; kt += 32) {
        __syncthreads();
        {
            int c = tid;                       // 64x32 A tile: 1 round
            int row = c >> 2, k8 = (c & 3) * 8;
            const bf16* g = A + (size_t)(mBase + row) * lda + (kt + k8);
            __builtin_amdgcn_global_load_lds(GPTR(g), LPTR(&As[0][0] + c * 8), 16, 0, 0);
        }
        #pragma unroll
        for (int i = 0; i < 2; i++) {          // 128x32 B tile: 2 rounds
            int c = tid + i * 256;
            int row = c >> 2, k8 = (c & 3) * 8;
            const bf16* g = Bt + (size_t)row * K + (kt + k8);
            __builtin_amdgcn_global_load_lds(GPTR(g), LPTR(&Bs[0][0] + c * 8), 16, 0, 0);
        }
        __syncthreads();

        bf16x8 af[2], bfr[4];
        #pragma unroll
        for (int m = 0; m < 2; m++) af[m]  = *(const bf16x8*)(&As[wr + m * 16 + lr][lk]);
        #pragma unroll
        for (int n = 0; n < 4; n++) bfr[n] = *(const bf16x8*)(&Bs[wc + n * 16 + lr][lk]);
        #pragma unroll
        for (int m = 0; m < 2; m++)
            #pragma unroll
            for (int n = 0; n < 4; n++)
                acc[m][n] = __builtin_amdgcn_mfma_f32_16x16x32_bf16(af[m], bfr[n], acc[m][n], 0, 0, 0);
    }

    const int lr4 = (lane >> 4) * 4;
    const int lc  = lane & 15;
    #pragma unroll
    for (int m = 0; m < 2; m++) {
        #pragma unroll
        for (int n = 0; n < 4; n++) {
            #pragma unroll
            for (int j = 0; j < 4; j++) {
                int row = mBase + wr + m * 16 + lr4 + j;
                int col = wc + n * 16 + lc;
                float v = acc[m][n][j];
                if (col >= sigcol) v = sigmoidf_(v);
                Cout[(size_t)row * ldc + col] = v;
            }
        }
    }
}

// ---------------- launch ----------------------------------------------------
extern "C" void kernel_launch(void* const* d_in, const int* in_sizes, int n_in,
                              void* d_out, int out_size, void* d_ws, size_t ws_size,
                              hipStream_t stream) {
    const float* x       = (const float*)d_in[0];
    const float* W_toP   = (const float*)d_in[1];
    const float* W_U     = (const float*)d_in[2];
    const float* W_F     = (const float*)d_in[3];
    const float* W_V     = (const float*)d_in[4];
    const float* W_lam   = (const float*)d_in[5];
    const float* B_mat   = (const float*)d_in[6];
    const float* C_mat   = (const float*)d_in[7];
    const float* W_fromP = (const float*)d_in[8];
    float* out = (float*)d_out;

    char* ws = (char*)d_ws;
    size_t off = 0;
    auto alloc = [&](size_t bytes) { void* p = ws + off; off = (off + bytes + 255) & ~255ULL; return p; };
    bf16*  TF  = (bf16*)alloc((size_t)Mm * 1024 * 2);
    float* UL  = (float*)alloc((size_t)Mm * 128 * 4);
    bf16*  sb  = (bf16*)alloc((size_t)Mm * PRr * 2);
    bf16*  W1t = (bf16*)alloc((size_t)1024 * 1024 * 2);
    bf16*  W3t = (bf16*)alloc((size_t)128 * 1024 * 2);
    bf16*  W2t = (bf16*)alloc((size_t)1024 * 576 * 2);
    float* CW  = (float*)alloc((size_t)PRr * Dd * 4);
    float* aggS = (float*)alloc((size_t)Bb * 64 * PRr * 4);
    float* aggP = (float*)alloc((size_t)Bb * 64 * PRr * 4);
    unsigned int* flags = (unsigned int*)alloc((size_t)Bb * 64 * 4);

    prep_all<<<dim3(4673), dim3(256), 0, stream>>>(W_toP, W_U, W_V, W_F,
                                                   B_mat, W_lam, W1t, W3t, CW, flags);
    prep_cw<<<dim3(4, 64, 8), dim3(256), 0, stream>>>(C_mat, W_fromP, CW);
    prep_w2<<<dim3(1024), dim3(576), 0, stream>>>(W_fromP, CW, W2t);

    // GEMM1: [t | Fg] = x @ [W_comb | W_F], f32 A reg-staged (half-tile pipeline)
    gemm256<0, 1><<<dim3((Mm / 256) * (1024 / 256)), 512, 0, stream>>>(
        nullptr, 0, nullptr, 0, 1 << 30, x, W1t, Dd, Dd, TF, 1024, Pp);

    // GEMM2: [u | lam] = [t|Fg] @ W3, sigmoid cols >= 64, f32 out (N=128)
    gemm_bt64<<<dim3(Mm / 64), 256, 0, stream>>>(
        TF, 1024, W3t, 1024, UL, 128, PRr);

    // fused parallel scan (decoupled lookback, single kernel)
    scan_fused<<<dim3(NCH / 4, Bb), dim3(256), 0, stream>>>(UL, aggS, aggP, flags, sb);

    // GEMM3: h = [t | s_seq] @ [W_fromP ; C@W_fromP], f32 out (K=576 split at 512)
    gemm256<2, 0><<<dim3((Mm / 256) * (1024 / 256)), 512, 0, stream>>>(
        TF, 1024, sb, PRr, Pp, nullptr, W2t, 576, 576, out, Dd, 1 << 30);
}

// Round 13
// 136.545 us; speedup vs baseline: 1.1271x; 1.1271x over previous
//
#include <hip/hip_runtime.h>
#include <hip/hip_bf16.h>

// Problem constants (B,T,D,P,ALPHA,PR) = (4,4096,1024,512,4,64)
#define Bb 4
#define Tt 4096
#define Dd 1024
#define Pp 512
#define PRr 64
#define Mm (Bb*Tt)   // 16384
#define NCH 256      // scan chunks per batch
#define CL  16       // chunk length = Tt/NCH

typedef __bf16 bf16;
typedef __bf16 bf16x8 __attribute__((ext_vector_type(8)));
typedef __bf16 bf16x4 __attribute__((ext_vector_type(4)));
typedef float f32x4 __attribute__((ext_vector_type(4)));

#define GPTR(p) (const __attribute__((address_space(1))) void*)(p)
#define LPTR(p) (__attribute__((address_space(3))) void*)(p)

__device__ __forceinline__ float sigmoidf_(float x) {
    return 1.0f / (1.0f + __expf(-x));
}

// ---------------- prep kernels (weights -> bf16, pre-transposed to N x K) ----

// Merged: W1t build [0,4096) + W3t build [4096,4608) + CW zeroing [4608,4672)
__global__ void prep_all(const float* __restrict__ W_toP, const float* __restrict__ W_U,
                         const float* __restrict__ W_V, const float* __restrict__ W_F,
                         const float* __restrict__ B_mat, const float* __restrict__ W_lam,
                         bf16* __restrict__ W1t, bf16* __restrict__ W3t,
                         float* __restrict__ CW) {
    int bid = blockIdx.x;
    if (bid < 4096) {
        int idx = bid * 256 + threadIdx.x;      // 1024*1024
        int n = idx >> 10, k = idx & 1023;
        float v;
        if (n < Pp) {
            int p = n;
            float4 u  = *(const float4*)(W_U + ((size_t)k * Pp + p) * 4);
            float4 wv = *(const float4*)(W_V + (size_t)p * 4);
            v = W_toP[(size_t)k * Pp + p] + u.x * wv.x + u.y * wv.y + u.z * wv.z + u.w * wv.w;
        } else {
            v = W_F[(size_t)k * Pp + (n - Pp)];
        }
        W1t[idx] = (bf16)v;
    } else if (bid < 4608) {
        int idx = (bid - 4096) * 256 + threadIdx.x;   // 128*1024
        int n = idx >> 10, k = idx & 1023;
        float v = 0.0f;
        if (n < PRr) { if (k < Pp) v = B_mat[(size_t)k * PRr + n]; }
        else         { if (k >= Pp) v = W_lam[(size_t)(k - Pp) * PRr + (n - PRr)]; }
        W3t[idx] = (bf16)v;
    } else {
        int i = (bid - 4608) * 256 + threadIdx.x;     // 64 blocks: 16384 f32x4
        ((f32x4*)CW)[i] = (f32x4){};
    }
}

// CW = C_mat (PR x P) @ W_fromP (P x D), split-K atomics.
// grid (4 col-chunks, 64 r, 8 p-chunks) = 2048 blocks x 256 thr.
__global__ void prep_cw(const float* __restrict__ C_mat, const float* __restrict__ W_fromP,
                        float* __restrict__ CW) {
    __shared__ float crow[64];
    int nc = blockIdx.x;           // 4
    int r  = blockIdx.y;           // 64
    int pc = blockIdx.z;           // 8
    int tid = threadIdx.x;         // 256
    if (tid < 64) crow[tid] = C_mat[(size_t)r * Pp + pc * 64 + tid];
    __syncthreads();
    int n = nc * 256 + tid;
    float acc = 0.0f;
    #pragma unroll 8
    for (int i = 0; i < 64; ++i)
        acc = fmaf(crow[i], W_fromP[(size_t)(pc * 64 + i) * Dd + n], acc);
    atomicAdd(&CW[(size_t)r * Dd + n], acc);
}

__global__ void prep_w2(const float* __restrict__ W_fromP, const float* __restrict__ CW,
                        bf16* __restrict__ W2t) {
    int n = blockIdx.x;          // 1024
    int k = threadIdx.x;         // 576
    float v = (k < Pp) ? W_fromP[(size_t)k * Dd + n]
                       : CW[(size_t)(k - Pp) * Dd + n];
    W2t[(size_t)n * 576 + k] = (bf16)v;
}

// ---------------- parallel scan: s_t = lam_t * s_{t-1} + u_t ----------------
// 256 chunks/batch of length 16; 4 chunks per 256-thread block.
// (R12's fused lookback scan regressed +16us: agent-scope spin/fence cost >
//  two launch gaps. 3-kernel bulk-parallel chain restored.)
__global__ void scan_phase1(const float* __restrict__ UL,
                            float* __restrict__ slocal, float* __restrict__ pprod,
                            float* __restrict__ carryS, float* __restrict__ carryP) {
    int b = blockIdx.y;
    int c = blockIdx.x * 4 + (threadIdx.x >> 6);
    int r = threadIdx.x & 63;
    const float* ulb = UL + ((size_t)b * Tt + (size_t)c * CL) * 128;
    float* sl = slocal + ((size_t)b * Tt + (size_t)c * CL) * PRr;
    float* pp = pprod  + ((size_t)b * Tt + (size_t)c * CL) * PRr;
    float uv[CL], lv[CL];
    #pragma unroll
    for (int i = 0; i < CL; i++) {
        uv[i] = ulb[(size_t)i * 128 + r];
        lv[i] = ulb[(size_t)i * 128 + 64 + r];
    }
    float s = 0.0f, p = 1.0f;
    #pragma unroll
    for (int i = 0; i < CL; i++) {
        s = fmaf(lv[i], s, uv[i]);
        p *= lv[i];
        sl[(size_t)i * PRr + r] = s;
        pp[(size_t)i * PRr + r] = p;
    }
    int ci = b * NCH + c;
    carryS[(size_t)ci * PRr + r] = s;
    carryP[(size_t)ci * PRr + r] = p;
}

__global__ void scan_phase2(const float* __restrict__ carryS, const float* __restrict__ carryP,
                            float* __restrict__ carryIn) {
    int b = blockIdx.x, r = threadIdx.x;
    float carry = 0.0f;
    for (int c0 = 0; c0 < NCH; c0 += 16) {
        float cs[16], cp[16];
        #pragma unroll
        for (int i = 0; i < 16; i++) {
            size_t idx = ((size_t)b * NCH + c0 + i) * PRr + r;
            cs[i] = carryS[idx];
            cp[i] = carryP[idx];
        }
        #pragma unroll
        for (int i = 0; i < 16; i++) {
            carryIn[((size_t)b * NCH + c0 + i) * PRr + r] = carry;
            carry = fmaf(cp[i], carry, cs[i]);
        }
    }
}

__global__ void scan_phase3(const float* __restrict__ slocal, const float* __restrict__ pprod,
                            const float* __restrict__ carryIn, bf16* __restrict__ sb) {
    int i = blockIdx.x * 256 + threadIdx.x;   // Mm*PRr
    int r = i & (PRr - 1);
    int row = i >> 6;
    int b = row >> 12;
    int t = row & (Tt - 1);
    int c = t / CL;
    float carry = carryIn[((size_t)b * NCH + c) * PRr + r];
    sb[i] = (bf16)fmaf(pprod[i], carry, slocal[i]);
}

// ---------------- 256x256 GEMM, 8-phase schedule (R10, frozen) --------------
// A row-major (M x K) bf16, split at ksplit between A0/A1 (tile-aligned);
// OR (AF32=1) A = Af in f32, reg-staged with on-the-fly bf16 convert.
// AF32 v3: HALF-TILE reg buffers H0,H1 (16 regs each = 32 total; no spill,
// VGPR 124) with 4-phase issue->write slack:
//   ph2(t): writeH0 (issued ph2(t-1), ~1400cyc slack > ~900cyc HBM), issue H0(t+2)
//   ph3(t): writeH1 (issued ph3(t-1)), issue H1(t+2), vmcnt(8) retires B(t+1)
// Measured R10/R11: GEMM1 ~57us, FETCH 41MB clean, MfmaUtil 22-23.
// AF32=0 path: exact R5 loop (45.7us measured). T2 swizzle both sides.
template <int EPI, int AF32>  // EPI 0: bf16 out + sigmoid col>=sigcol ; 2: f32 plain
__global__ __launch_bounds__(512, 2) void gemm256(
    const bf16* __restrict__ A0, int lda0,
    const bf16* __restrict__ A1, int lda1, int ksplit,
    const float* __restrict__ Af,
    const bf16* __restrict__ Bt, int ldb, int K,
    void* __restrict__ Cout, int ldc, int sigcol) {

    __shared__ bf16 As[2][256 * 64];
    __shared__ bf16 Bs[2][256 * 64];

    const int tid  = threadIdx.x;
    const int lane = tid & 63;
    const int wid  = tid >> 6;
    const int wm   = wid >> 2;        // 0..1
    const int wn   = wid & 3;         // 0..3

    // bijective XCD swizzle (grid multiple of 8)
    const int cpx = gridDim.x >> 3;
    const int bid = blockIdx.x;
    const int swz = (bid & 7) * cpx + (bid >> 3);
    const int mBase = (swz >> 2) * 256;
    const int nBase = (swz & 3) * 256;

    const int lr  = lane & 15;
    const int q16 = (lane >> 4) * 16;   // byte col offset of fragment

    auto srcA = [&](int kt, const bf16*& src, int& lda, int& kc) {
        if (kt < ksplit) { src = A0; lda = lda0; kc = kt; }
        else             { src = A1; lda = lda1; kc = kt - ksplit; }
    };

    // stage one 8KB round: linear LDS dest, inverse-swizzled global src (rule 21)
    auto stage = [&](const bf16* src, int lda, int kc, int rowBase, bf16* lbuf, int rd) {
        int d = rd * 8192 + tid * 16;             // phys byte (linear)
        int L = d ^ (((d >> 7) & 7) << 4);        // logical byte
        int r = L >> 7;
        int c = (L & 127) >> 1;
        const bf16* g = src + (size_t)(rowBase + r) * lda + (kc + c);
        __builtin_amdgcn_global_load_lds(GPTR(g), LPTR((char*)lbuf + d), 16, 0, 0);
    };

    auto frag = [&](const bf16* lbuf, int r, int cb) -> bf16x8 {
        int flat = r * 128 + cb;
        int phys = flat ^ (((flat >> 7) & 7) << 4);
        return *(const bf16x8*)((const char*)lbuf + phys);
    };

    // AF32 A-path: per-round logical (row,col) for this thread's 16B dest slot
    int rrA[4], ccA[4];
    #pragma unroll
    for (int rd = 0; rd < 4; ++rd) {
        int d = rd * 8192 + tid * 16;
        int L = d ^ (((d >> 7) & 7) << 4);
        rrA[rd] = L >> 7;
        ccA[rd] = (L & 127) >> 1;
    }
    f32x4 H0[4], H1[4];   // two half-tile staging buffers (rounds 0,1 / 2,3)

    auto issueH = [&](f32x4 (&v)[4], int kc, int rdb) {
        #pragma unroll
        for (int rd = 0; rd < 2; ++rd) {
            const float* g = Af + (size_t)(mBase + rrA[rdb + rd]) * Dd + kc + ccA[rdb + rd];
            v[2 * rd]     = *(const f32x4*)(g);
            v[2 * rd + 1] = *(const f32x4*)(g + 4);
        }
        asm volatile("" ::: "memory");   // pin loads here
    };
    auto writeH = [&](f32x4 (&v)[4], bf16* lbuf, int rdb) {
        #pragma unroll
        for (int rd = 0; rd < 2; ++rd) {
            bf16x8 o;
            #pragma unroll
            for (int j = 0; j < 4; ++j) {
                o[j]     = (bf16)v[2 * rd][j];
                o[j + 4] = (bf16)v[2 * rd + 1][j];
            }
            *(bf16x8*)((char*)lbuf + (rdb + rd) * 8192 + tid * 16) = o;
        }
    };

    const int NT = K / 64;

    // prologue
    if (AF32) {
        issueH(H0, 0, 0); issueH(H1, 0, 2);
        stage(Bt, ldb, 0, nBase, Bs[0], 0); stage(Bt, ldb, 0, nBase, Bs[0], 1);
        stage(Bt, ldb, 0, nBase, Bs[0], 2); stage(Bt, ldb, 0, nBase, Bs[0], 3);
        writeH(H0, As[0], 0);                // auto vmcnt: waits H0
        writeH(H1, As[0], 2);                // auto vmcnt: waits H1
        if (NT > 1) { issueH(H0, 64, 0); issueH(H1, 64, 2); }
        asm volatile("s_waitcnt lgkmcnt(0)" ::: "memory");
        if (NT > 1) asm volatile("s_waitcnt vmcnt(8)" ::: "memory");  // retire B(0)
        else        asm volatile("s_waitcnt vmcnt(0)" ::: "memory");
    } else {
        const bf16* sa; int la, kc; srcA(0, sa, la, kc);
        stage(sa, la, kc, mBase, As[0], 0); stage(sa, la, kc, mBase, As[0], 2);
        stage(Bt, ldb, 0, nBase, Bs[0], 0); stage(Bt, ldb, 0, nBase, Bs[0], 1);
        stage(Bt, ldb, 0, nBase, Bs[0], 2); stage(Bt, ldb, 0, nBase, Bs[0], 3);
        stage(sa, la, kc, mBase, As[0], 1); stage(sa, la, kc, mBase, As[0], 3);
        asm volatile("s_waitcnt vmcnt(2)" ::: "memory");
    }
    __builtin_amdgcn_s_barrier();

    f32x4 acc[8][4] = {};
    bf16x8 a[4], b0[4], b1[4];

#define MFMA16(AOFF, AV, BV)                                                          \
    _Pragma("unroll")                                                                 \
    for (int m_ = 0; m_ < 4; ++m_)                                                    \
        _Pragma("unroll")                                                             \
        for (int n_ = 0; n_ < 4; ++n_)                                                \
            acc[m_ + AOFF][n_] = __builtin_amdgcn_mfma_f32_16x16x32_bf16(             \
                AV[m_], BV[n_], acc[m_ + AOFF][n_], 0, 0, 0);

    if (AF32) {
        for (int t = 0; t < NT; ++t) {
            bf16* Ac = As[t & 1];       bf16* Bc = Bs[t & 1];
            bf16* An = As[(t + 1) & 1]; bf16* Bn = Bs[(t + 1) & 1];
            const bool hn  = (t + 1 < NT);
            const bool hn2 = (t + 2 < NT);
            const int ktn  = (t + 1) * 64;
            const int ktn2 = (t + 2) * 64;

            // ---- phase 0: G0 = (m0-3, kk0) ----
            #pragma unroll
            for (int i = 0; i < 4; ++i) a[i]  = frag(Ac, wm * 128 + i * 16 + lr, q16);
            #pragma unroll
            for (int i = 0; i < 4; ++i) b0[i] = frag(Bc, wn * 64 + i * 16 + lr, q16);
            if (hn) { stage(Bt, ldb, ktn, nBase, Bn, 0); stage(Bt, ldb, ktn, nBase, Bn, 1); }
            __builtin_amdgcn_s_barrier();
            __builtin_amdgcn_s_setprio(1);
            MFMA16(0, a, b0)
            __builtin_amdgcn_s_setprio(0);
            __builtin_amdgcn_s_barrier();

            // ---- phase 1: G1 = (m4-7, kk0) ----
            #pragma unroll
            for (int i = 0; i < 4; ++i) a[i] = frag(Ac, wm * 128 + (i + 4) * 16 + lr, q16);
            if (hn) { stage(Bt, ldb, ktn, nBase, Bn, 2); stage(Bt, ldb, ktn, nBase, Bn, 3); }
            __builtin_amdgcn_s_barrier();
            __builtin_amdgcn_s_setprio(1);
            MFMA16(4, a, b0)
            __builtin_amdgcn_s_setprio(0);
            __builtin_amdgcn_s_barrier();

            // ---- phase 2: G2 = (m0-3, kk1); writeH0 (4-phase slack), issue H0(t+2)
            #pragma unroll
            for (int i = 0; i < 4; ++i) a[i]  = frag(Ac, wm * 128 + i * 16 + lr, 64 + q16);
            #pragma unroll
            for (int i = 0; i < 4; ++i) b1[i] = frag(Bc, wn * 64 + i * 16 + lr, 64 + q16);
            if (hn)  writeH(H0, An, 0);            // auto vmcnt(8): retires H0
            if (hn2) issueH(H0, ktn2, 0);
            if (hn)  asm volatile("s_waitcnt lgkmcnt(0)" ::: "memory");
            __builtin_amdgcn_s_barrier();
            __builtin_amdgcn_s_setprio(1);
            MFMA16(0, a, b1)
            __builtin_amdgcn_s_setprio(0);
            __builtin_amdgcn_s_barrier();

            // ---- phase 3: G3 = (m4-7, kk1); writeH1, issue H1(t+2), retire B(t+1)
            #pragma unroll
            for (int i = 0; i < 4; ++i) a[i] = frag(Ac, wm * 128 + (i + 4) * 16 + lr, 64 + q16);
            if (hn)  writeH(H1, An, 2);            // auto vmcnt(8): retires H1
            if (hn2) issueH(H1, ktn2, 2);
            if (hn)  asm volatile("s_waitcnt lgkmcnt(0)" ::: "memory");
            if (hn2)      asm volatile("s_waitcnt vmcnt(8)" ::: "memory");  // retire B(t+1)
            else if (hn)  asm volatile("s_waitcnt vmcnt(0)" ::: "memory");  // tail drain
            __builtin_amdgcn_s_barrier();
            __builtin_amdgcn_s_setprio(1);
            MFMA16(4, a, b1)
            __builtin_amdgcn_s_setprio(0);
            __builtin_amdgcn_s_barrier();
        }
    } else {
        for (int t = 0; t < NT; ++t) {
            bf16* Ac = As[t & 1];       bf16* Bc = Bs[t & 1];
            bf16* An = As[(t + 1) & 1]; bf16* Bn = Bs[(t + 1) & 1];
            const bool hn = (t + 1 < NT);
            const bf16* sa = A0; int la = lda0, kc = 0;
            if (hn) srcA((t + 1) * 64, sa, la, kc);
            const int ktn = (t + 1) * 64;

            // ---- phase 0: G0 = (m0-3, kk0) ----
            #pragma unroll
            for (int i = 0; i < 4; ++i) a[i]  = frag(Ac, wm * 128 + i * 16 + lr, q16);
            #pragma unroll
            for (int i = 0; i < 4; ++i) b0[i] = frag(Bc, wn * 64 + i * 16 + lr, q16);
            if (hn) {
                stage(sa, la, kc, mBase, An, 0); stage(sa, la, kc, mBase, An, 2);
                asm volatile("s_waitcnt vmcnt(2)" ::: "memory");   // retire A1,A3 of cur
            } else {
                asm volatile("s_waitcnt vmcnt(0)" ::: "memory");   // last tile: drain
            }
            __builtin_amdgcn_s_barrier();
            __builtin_amdgcn_s_setprio(1);
            MFMA16(0, a, b0)
            __builtin_amdgcn_s_setprio(0);
            __builtin_amdgcn_s_barrier();

            // ---- phase 1: G1 = (m4-7, kk0) ----
            #pragma unroll
            for (int i = 0; i < 4; ++i) a[i] = frag(Ac, wm * 128 + (i + 4) * 16 + lr, q16);
            if (hn) { stage(Bt, ldb, ktn, nBase, Bn, 0); stage(Bt, ldb, ktn, nBase, Bn, 1); }
            __builtin_amdgcn_s_barrier();
            __builtin_amdgcn_s_setprio(1);
            MFMA16(4, a, b0)
            __builtin_amdgcn_s_setprio(0);
            __builtin_amdgcn_s_barrier();

            // ---- phase 2: G2 = (m0-3, kk1) ----
            #pragma unroll
            for (int i = 0; i < 4; ++i) a[i]  = frag(Ac, wm * 128 + i * 16 + lr, 64 + q16);
            #pragma unroll
            for (int i = 0; i < 4; ++i) b1[i] = frag(Bc, wn * 64 + i * 16 + lr, 64 + q16);
            if (hn) { stage(Bt, ldb, ktn, nBase, Bn, 2); stage(Bt, ldb, ktn, nBase, Bn, 3); }
            __builtin_amdgcn_s_barrier();
            __builtin_amdgcn_s_setprio(1);
            MFMA16(0, a, b1)
            __builtin_amdgcn_s_setprio(0);
            __builtin_amdgcn_s_barrier();

            // ---- phase 3: G3 = (m4-7, kk1) ----
            #pragma unroll
            for (int i = 0; i < 4; ++i) a[i] = frag(Ac, wm * 128 + (i + 4) * 16 + lr, 64 + q16);
            if (hn) {
                stage(sa, la, kc, mBase, An, 1); stage(sa, la, kc, mBase, An, 3);
                asm volatile("s_waitcnt vmcnt(2)" ::: "memory");   // retire A0,A2,B0..B3 of next
            }
            __builtin_amdgcn_s_barrier();
            __builtin_amdgcn_s_setprio(1);
            MFMA16(4, a, b1)
            __builtin_amdgcn_s_setprio(0);
            __builtin_amdgcn_s_barrier();
        }
    }
#undef MFMA16

    // epilogue
    const int lr4 = (lane >> 4) * 4;
    #pragma unroll
    for (int m = 0; m < 8; ++m) {
        #pragma unroll
        for (int n = 0; n < 4; ++n) {
            #pragma unroll
            for (int j = 0; j < 4; ++j) {
                int row = mBase + wm * 128 + m * 16 + lr4 + j;
                int col = nBase + wn * 64 + n * 16 + lr;
                float v = acc[m][n][j];
                if (EPI == 0) {
                    if (col >= sigcol) v = sigmoidf_(v);
                    ((bf16*)Cout)[(size_t)row * ldc + col] = (bf16)v;
                } else {
                    ((float*)Cout)[(size_t)row * ldc + col] = v;
                }
            }
        }
    }
}

// ---------------- 64x128 GEMM for GEMM2 (N=128): full-chip grid -------------
__global__ __launch_bounds__(256) void gemm_bt64(
    const bf16* __restrict__ A, int lda,
    const bf16* __restrict__ Bt, int K,
    float* __restrict__ Cout, int ldc, int sigcol) {

    __shared__ bf16 As[64][32];
    __shared__ bf16 Bs[128][32];

    const int tid  = threadIdx.x;
    const int lane = tid & 63;
    const int wid  = tid >> 6;
    const int wr   = (wid >> 1) * 32;
    const int wc   = (wid & 1) * 64;
    const int mBase = blockIdx.x * 64;

    f32x4 acc[2][4] = {};

    const int lr = lane & 15;
    const int lk = (lane >> 4) * 8;

    for (int kt = 0; kt < K; kt += 32) {
        __syncthreads();
        {
            int c = tid;                       // 64x32 A tile: 1 round
            int row = c >> 2, k8 = (c & 3) * 8;
            const bf16* g = A + (size_t)(mBase + row) * lda + (kt + k8);
            __builtin_amdgcn_global_load_lds(GPTR(g), LPTR(&As[0][0] + c * 8), 16, 0, 0);
        }
        #pragma unroll
        for (int i = 0; i < 2; i++) {          // 128x32 B tile: 2 rounds
            int c = tid + i * 256;
            int row = c >> 2, k8 = (c & 3) * 8;
            const bf16* g = Bt + (size_t)row * K + (kt + k8);
            __builtin_amdgcn_global_load_lds(GPTR(g), LPTR(&Bs[0][0] + c * 8), 16, 0, 0);
        }
        __syncthreads();

        bf16x8 af[2], bfr[4];
        #pragma unroll
        for (int m = 0; m < 2; m++) af[m]  = *(const bf16x8*)(&As[wr + m * 16 + lr][lk]);
        #pragma unroll
        for (int n = 0; n < 4; n++) bfr[n] = *(const bf16x8*)(&Bs[wc + n * 16 + lr][lk]);
        #pragma unroll
        for (int m = 0; m < 2; m++)
            #pragma unroll
            for (int n = 0; n < 4; n++)
                acc[m][n] = __builtin_amdgcn_mfma_f32_16x16x32_bf16(af[m], bfr[n], acc[m][n], 0, 0, 0);
    }

    const int lr4 = (lane >> 4) * 4;
    const int lc  = lane & 15;
    #pragma unroll
    for (int m = 0; m < 2; m++) {
        #pragma unroll
        for (int n = 0; n < 4; n++) {
            #pragma unroll
            for (int j = 0; j < 4; j++) {
                int row = mBase + wr + m * 16 + lr4 + j;
                int col = wc + n * 16 + lc;
                float v = acc[m][n][j];
                if (col >= sigcol) v = sigmoidf_(v);
                Cout[(size_t)row * ldc + col] = v;
            }
        }
    }
}

// ---------------- launch ----------------------------------------------------
extern "C" void kernel_launch(void* const* d_in, const int* in_sizes, int n_in,
                              void* d_out, int out_size, void* d_ws, size_t ws_size,
                              hipStream_t stream) {
    const float* x       = (const float*)d_in[0];
    const float* W_toP   = (const float*)d_in[1];
    const float* W_U     = (const float*)d_in[2];
    const float* W_F     = (const float*)d_in[3];
    const float* W_V     = (const float*)d_in[4];
    const float* W_lam   = (const float*)d_in[5];
    const float* B_mat   = (const float*)d_in[6];
    const float* C_mat   = (const float*)d_in[7];
    const float* W_fromP = (const float*)d_in[8];
    float* out = (float*)d_out;

    char* ws = (char*)d_ws;
    size_t off = 0;
    auto alloc = [&](size_t bytes) { void* p = ws + off; off = (off + bytes + 255) & ~255ULL; return p; };
    bf16*  TF  = (bf16*)alloc((size_t)Mm * 1024 * 2);
    float* UL  = (float*)alloc((size_t)Mm * 128 * 4);
    bf16*  sb  = (bf16*)alloc((size_t)Mm * PRr * 2);
    bf16*  W1t = (bf16*)alloc((size_t)1024 * 1024 * 2);
    bf16*  W3t = (bf16*)alloc((size_t)128 * 1024 * 2);
    bf16*  W2t = (bf16*)alloc((size_t)1024 * 576 * 2);
    float* CW  = (float*)alloc((size_t)PRr * Dd * 4);
    float* slocal = (float*)alloc((size_t)Mm * PRr * 4);
    float* pprod  = (float*)alloc((size_t)Mm * PRr * 4);
    float* carryS = (float*)alloc((size_t)Bb * NCH * PRr * 4);
    float* carryP = (float*)alloc((size_t)Bb * NCH * PRr * 4);
    float* carryI = (float*)alloc((size_t)Bb * NCH * PRr * 4);

    prep_all<<<dim3(4672), dim3(256), 0, stream>>>(W_toP, W_U, W_V, W_F,
                                                   B_mat, W_lam, W1t, W3t, CW);
    prep_cw<<<dim3(4, 64, 8), dim3(256), 0, stream>>>(C_mat, W_fromP, CW);
    prep_w2<<<dim3(1024), dim3(576), 0, stream>>>(W_fromP, CW, W2t);

    // GEMM1: [t | Fg] = x @ [W_comb | W_F], f32 A reg-staged (half-tile pipeline)
    gemm256<0, 1><<<dim3((Mm / 256) * (1024 / 256)), 512, 0, stream>>>(
        nullptr, 0, nullptr, 0, 1 << 30, x, W1t, Dd, Dd, TF, 1024, Pp);

    // GEMM2: [u | lam] = [t|Fg] @ W3, sigmoid cols >= 64, f32 out (N=128)
    gemm_bt64<<<dim3(Mm / 64), 256, 0, stream>>>(
        TF, 1024, W3t, 1024, UL, 128, PRr);

    // parallel scan
    scan_phase1<<<dim3(NCH / 4, Bb), dim3(256), 0, stream>>>(UL, slocal, pprod, carryS, carryP);
    scan_phase2<<<dim3(Bb), dim3(PRr), 0, stream>>>(carryS, carryP, carryI);
    scan_phase3<<<dim3(Mm * PRr / 256), dim3(256), 0, stream>>>(slocal, pprod, carryI, sb);

    // GEMM3: h = [t | s_seq] @ [W_fromP ; C@W_fromP], f32 out (K=576 split at 512)
    gemm256<2, 0><<<dim3((Mm / 256) * (1024 / 256)), 512, 0, stream>>>(
        TF, 1024, sb, PRr, Pp, nullptr, W2t, 576, 576, out, Dd, 1 << 30);
}